// Round 1
// 75.520 us; speedup vs baseline: 1.0320x; 1.0320x over previous
//
#include <hip/hip_runtime.h>

#define NQ 10
#define NL 3

typedef float v2f __attribute__((ext_vector_type(2)));

__device__ __forceinline__ int   f2i(float v) { union { float f; int i; } u; u.f = v; return u.i; }
__device__ __forceinline__ float i2f(int v)   { union { int i; float f; } u; u.i = v; return u.f; }

// ---- packed-f32 complex helpers (gfx950 full-rate VOP3P) -------------------
// cmul: (a.x+ia.y)*(b.x+ib.y). Same fma ordering as scalar version:
//   re = ax*bx fma(-ay,by)   im = ax*by fma(ay,bx)
__device__ __forceinline__ v2f cmul(v2f a, v2f b) {
    v2f d;
    asm("v_pk_mul_f32 %0, %1, %2 op_sel:[0,0] op_sel_hi:[0,1]"
        : "=v"(d) : "v"(a), "v"(b));                       // (ax*bx, ax*by)
    asm("v_pk_fma_f32 %0, %1, %2, %0 op_sel:[1,1,0] op_sel_hi:[1,0,1] neg_lo:[0,1,0]"
        : "+v"(d) : "v"(a), "v"(b));                       // (+= -ay*by, += ay*bx)
    return d;
}

// A*cs.x + B*cs.y elementwise (2 instr, replaces 4 scalar FMAs)
__device__ __forceinline__ v2f pk_ab(v2f A, v2f B, v2f cs) {
    v2f d;
    asm("v_pk_mul_f32 %0, %1, %2 op_sel:[0,1] op_sel_hi:[1,1]"
        : "=v"(d) : "v"(B), "v"(cs));                      // (B.x*s, B.y*s)
    asm("v_pk_fma_f32 %0, %1, %2, %0 op_sel:[0,0,0] op_sel_hi:[1,0,1]"
        : "+v"(d) : "v"(A), "v"(cs));                      // += (A.x*c, A.y*c)
    return d;
}
// A*cs.x - B*cs.y elementwise
__device__ __forceinline__ v2f pk_ab_n(v2f A, v2f B, v2f cs) {
    v2f d;
    asm("v_pk_mul_f32 %0, %1, %2 op_sel:[0,1] op_sel_hi:[1,1] neg_lo:[1,0] neg_hi:[1,0]"
        : "=v"(d) : "v"(B), "v"(cs));                      // (-B.x*s, -B.y*s)
    asm("v_pk_fma_f32 %0, %1, %2, %0 op_sel:[0,0,0] op_sel_hi:[1,0,1]"
        : "+v"(d) : "v"(A), "v"(cs));
    return d;
}

template<int C> __device__ __forceinline__ int dppm(int v) {
    return __builtin_amdgcn_mov_dpp(v, C, 0xF, 0xF, false);
}

// ---- lane exchange by xor mask LM. Single-DPP only for LM 1,2,3 (2-cyc VALU,
// zero latency). Everything else goes to the DS pipe (swizzle <32, bpermute
// >=32) to keep VALU free for the FMA stream. (R8-verified best routing.) ----
template<int LM>
__device__ __forceinline__ v2f xlane(v2f v, int baddr) {
    if constexpr (LM == 0) return v;
    int x = f2i(v.x), y = f2i(v.y);
    if constexpr (LM == 1)       { x = dppm<177>(x); y = dppm<177>(y); }
    else if constexpr (LM == 2)  { x = dppm<78>(x);  y = dppm<78>(y); }
    else if constexpr (LM == 3)  { x = dppm<27>(x);  y = dppm<27>(y); }
    else if constexpr (LM < 32) {
        constexpr int off = (LM << 10) | 0x1F;   // BitMode xor
        x = __builtin_amdgcn_ds_swizzle(x, off);
        y = __builtin_amdgcn_ds_swizzle(y, off);
    } else {
        x = __builtin_amdgcn_ds_bpermute(baddr, x);
        y = __builtin_amdgcn_ds_bpermute(baddr, y);
    }
    return (v2f){ i2f(x), i2f(y) };
}

// Generalized single-qubit gate under GF(2) index transform (masks verified
// R2-R11). Packed-f32 math: 4 VOP3P per amp (was 8 scalar v_fma), identical
// IEEE rounding order. Slot parity SP is compile-time so coefficient choice
// is free.
template<int MASK, int RMASK>
__device__ __forceinline__ void apply_gate(v2f (&a)[16], float4 r0, float4 r1,
                                           float cq, float sq, int lane)
{
    constexpr int LM = (MASK >> 4) & 63;
    constexpr int JM = MASK & 15;
    constexpr int RH = (RMASK >> 4) & 63;
    constexpr int RL = RMASK & 15;

    // fuse Rot * RY(c,s): 8 packed instr (was 16 scalar FMA)
    const v2f vcs = { cq, sq };
    const v2f r0a = { r0.x, r0.y }, r0b = { r0.z, r0.w };
    const v2f r1a = { r1.x, r1.y }, r1b = { r1.z, r1.w };
    const v2f g00 = pk_ab  (r0a, r0b, vcs);   // (g00r, g00i)
    const v2f g01 = pk_ab_n(r0b, r0a, vcs);   // (g01r, g01i)
    const v2f g10 = pk_ab  (r1a, r1b, vcs);
    const v2f g11 = pk_ab_n(r1b, r1a, vcs);

    const bool lp = (RH != 0) && (__popc(lane & RH) & 1);
    // parity-0 (total parity even) and parity-1 coefficient sets, (re,im) pairs
    const v2f A0 = lp ? g11 : g00;
    const v2f B0 = lp ? g10 : g01;
    const v2f A1 = lp ? g00 : g11;
    const v2f B1 = lp ? g01 : g10;

    const int baddr = ((lane ^ LM) << 2);

    // phase 1: all partner values (independent -> batched DS/DPP issue)
    v2f o[16];
    #pragma unroll
    for (int j = 0; j < 16; ++j) o[j] = xlane<LM>(a[j ^ JM], baddr);

    // phase 2: new = A (x) a + B (x) o (complex), 4 packed FMA-class instr/amp
#define QNN_F(J) { constexpr int SP_ = __builtin_popcount((J) & RL) & 1;      \
    const v2f CA = SP_ ? A1 : A0;                                             \
    const v2f CB = SP_ ? B1 : B0;                                             \
    const v2f av = a[J]; const v2f ov = o[J];                                 \
    v2f d;                                                                    \
    asm("v_pk_mul_f32 %0, %1, %2 op_sel:[0,0] op_sel_hi:[0,1]"                \
        : "=v"(d) : "v"(CA), "v"(av));          /* (Ar*ar, Ar*ai) */          \
    asm("v_pk_fma_f32 %0, %1, %2, %0 op_sel:[1,1,0] op_sel_hi:[1,0,1] neg_lo:[0,1,0]" \
        : "+v"(d) : "v"(CA), "v"(av));          /* (-Ai*ai, +Ai*ar) */        \
    asm("v_pk_fma_f32 %0, %1, %2, %0 op_sel:[0,0,0] op_sel_hi:[0,1,1]"        \
        : "+v"(d) : "v"(CB), "v"(ov));          /* (+Br*pr, +Br*pi) */        \
    asm("v_pk_fma_f32 %0, %1, %2, %0 op_sel:[1,1,0] op_sel_hi:[1,0,1] neg_lo:[0,1,0]" \
        : "+v"(d) : "v"(CB), "v"(ov));          /* (-Bi*pi, +Bi*pr) */        \
    a[J] = d; }
    QNN_F(0) QNN_F(1) QNN_F(2) QNN_F(3) QNN_F(4) QNN_F(5) QNN_F(6) QNN_F(7)
    QNN_F(8) QNN_F(9) QNN_F(10) QNN_F(11) QNN_F(12) QNN_F(13) QNN_F(14) QNN_F(15)
#undef QNN_F
}

__global__ __launch_bounds__(256, 4)
void qnn_kernel(const float* __restrict__ x, const float* __restrict__ w,
                float* __restrict__ out)
{
    __shared__ float4 rotL[NL * NQ][2];   // (R00,R01) | (R10,R11)

    const int t    = threadIdx.x;
    const int lane = t & 63;
    const int b    = blockIdx.x * 4 + (t >> 6);   // one wave per batch element

    if (t < NL * NQ) {
        const float* wp = w + t * 3;
        float phi = wp[0], th = wp[1], om = wp[2];
        float ct = cosf(th * 0.5f), st = sinf(th * 0.5f);
        float ap = (phi + om) * 0.5f, am = (phi - om) * 0.5f;
        float cap = cosf(ap), sap = sinf(ap);
        float cam = cosf(am), sam = sinf(am);
        rotL[t][0] = make_float4(cap * ct, -sap * ct, -cam * st, -sam * st);
        rotL[t][1] = make_float4(cam * st, -sam * st,  cap * ct,  sap * ct);
    }
    __syncthreads();

    // ---- per-batch RY cos/sin (wave-uniform -> SGPR via readfirstlane) ----
    const float* xb = x + (size_t)__builtin_amdgcn_readfirstlane(b * NQ);
    float c_[NQ], s_[NQ];
    #pragma unroll
    for (int q = 0; q < NQ; ++q) {
        float xv = xb[q] * 0.5f;
        c_[q] = i2f(__builtin_amdgcn_readfirstlane(f2i(__cosf(xv))));
        s_[q] = i2f(__builtin_amdgcn_readfirstlane(f2i(__sinf(xv))));
    }

    // ---- layer 1 analytic: product state amp[p] = prod_q col0(G_q)[bit_q(p)] ----
    v2f c0[4], c1[4];
    v2f Ln = {1.f, 0.f};
    #pragma unroll
    for (int q = 0; q < NQ; ++q) {
        float4 r0 = rotL[q][0], r1 = rotL[q][1];
        const v2f vcs = { c_[q], s_[q] };
        const v2f r0a = { r0.x, r0.y }, r0b = { r0.z, r0.w };
        const v2f r1a = { r1.x, r1.y }, r1b = { r1.z, r1.w };
        v2f g0 = pk_ab(r0a, r0b, vcs);
        v2f g1 = pk_ab(r1a, r1b, vcs);
        if (q < 4) { c0[q] = g0; c1[q] = g1; }
        else {
            v2f gg = ((lane >> (q - 4)) & 1) ? g1 : g0;
            Ln = (q == 4) ? gg : cmul(Ln, gg);
        }
    }
    v2f S01[4], SH[4];
    #pragma unroll
    for (int j = 0; j < 4; ++j)
        S01[j] = cmul((j & 1) ? c1[0] : c0[0], (j & 2) ? c1[1] : c0[1]);
    #pragma unroll
    for (int h = 0; h < 4; ++h)
        SH[h] = cmul(cmul((h & 1) ? c1[2] : c0[2], (h & 2) ? c1[3] : c0[3]), Ln);
    v2f a[16];
    #pragma unroll
    for (int j = 0; j < 16; ++j)
        a[j] = cmul(S01[j & 3], SH[j >> 2]);

    // ---- layers 2..3 (masks + parities verified in R2/R3/R5/R8) ----
#define GATE(IDX, Q, MASK, RMASK) \
    apply_gate<MASK, RMASK>(a, rotL[IDX][0], rotL[IDX][1], c_[Q], s_[Q], lane);
    GATE(10, 0, 0x003, 0x3FE)  GATE(11, 1, 0x006, 0x003)
    GATE(12, 2, 0x00C, 0x007)  GATE(13, 3, 0x018, 0x00F)
    GATE(14, 4, 0x030, 0x01F)  GATE(15, 5, 0x060, 0x03F)
    GATE(16, 6, 0x0C0, 0x07F)  GATE(17, 7, 0x180, 0x0FF)
    GATE(18, 8, 0x300, 0x1FF)  GATE(19, 9, 0x203, 0x3FF)
    GATE(20, 0, 0x005, 0x2AB)  GATE(21, 1, 0x00A, 0x3FD)
    GATE(22, 2, 0x014, 0x3FA)  GATE(23, 3, 0x028, 0x3F5)
    GATE(24, 4, 0x050, 0x3EA)  GATE(25, 5, 0x0A0, 0x3D5)
    GATE(26, 6, 0x140, 0x3AA)  GATE(27, 7, 0x280, 0x355)
    GATE(28, 8, 0x103, 0x2AA)  GATE(29, 9, 0x206, 0x155)
#undef GATE

    // ---- probabilities + 4-bit Walsh-Hadamard over slots ----
    float P[16];
    #pragma unroll
    for (int j = 0; j < 16; ++j)
        P[j] = fmaf(a[j].x, a[j].x, a[j].y * a[j].y);
    #pragma unroll
    for (int bit = 0; bit < 4; ++bit) {
        #pragma unroll
        for (int j = 0; j < 16; ++j)
            if (!(j & (1 << bit))) {
                int k = j | (1 << bit);
                float u = P[j], v = P[k];
                P[j] = u + v;
                P[k] = u - v;
            }
    }

    const int bp32 = ((lane ^ 32) << 2);
    float vout = 0.f;
#define MEAS(Q, RM)                                                           \
    { constexpr int RH_ = ((RM) >> 4) & 63;                                   \
      constexpr int RL_ = (RM) & 15;                                          \
      float v = P[RL_];                                                       \
      if (__popc(lane & RH_) & 1) v = -v;                                     \
      v += i2f(dppm<177>(f2i(v)));                 /* xor1  */                \
      v += i2f(dppm<78>(f2i(v)));                  /* xor2  */                \
      v += i2f(dppm<321>(dppm<27>(f2i(v))));       /* xor4 = 7^3 */           \
      v += i2f(dppm<320>(dppm<321>(f2i(v))));      /* xor8 = 15^7 */          \
      v += i2f(__builtin_amdgcn_ds_swizzle(f2i(v), (16 << 10) | 0x1F));       \
      v += i2f(__builtin_amdgcn_ds_bpermute(bp32, f2i(v)));                   \
      if (lane == (Q)) vout = v; }
    MEAS(0, 0x0CD) MEAS(1, 0x156) MEAS(2, 0x2AC) MEAS(3, 0x159)
    MEAS(4, 0x2B3) MEAS(5, 0x166) MEAS(6, 0x2CC) MEAS(7, 0x199)
    MEAS(8, 0x333) MEAS(9, 0x266)
#undef MEAS

    if (lane < NQ) out[b * NQ + lane] = vout;
}

extern "C" void kernel_launch(void* const* d_in, const int* in_sizes, int n_in,
                              void* d_out, int out_size, void* d_ws, size_t ws_size,
                              hipStream_t stream) {
    const float* x = (const float*)d_in[0];   // (4096, 10) f32
    const float* w = (const float*)d_in[1];   // (3, 10, 3) f32
    float* out = (float*)d_out;               // (4096, 10) f32
    const int B = in_sizes[0] / NQ;           // 4096
    qnn_kernel<<<B / 4, 256, 0, stream>>>(x, w, out);
}